// Round 3
// baseline (85.138 us; speedup 1.0000x reference)
//
#include <hip/hip_runtime.h>

// Problem constants (from setup_inputs): B=8, N=2048, n_C=n_T=1024, D=1.
#define BB   8
#define NN   2048
#define NC   1024
#define TOT  (BB * NN)          // 16384 points total
#define PW   8                  // points per wave
#define NWAVE (TOT / PW)        // 2048 waves
#define NBLK  (NWAVE / 4)       // 512 blocks of 4 waves

// Output layout (flat float32, reference tuple order):
//   y_diff[TOT], x_diff[TOT], d_out[TOT*2], x_n[TOT], y_n[TOT]
#define OFF_YDIFF 0
#define OFF_XDIFF (TOT)
#define OFF_DOUT  (2 * TOT)
#define OFF_XN    (4 * TOT)
#define OFF_YN    (5 * TOT)

// Lexicographic (dist, idx) merge of two sorted top-2 lists -> top-2 of union.
__device__ __forceinline__ void lex_merge(float& d1, int& i1, float& d2, int& i2,
                                          float od1, int oi1, float od2, int oi2)
{
    const bool  lt1 = (od1 < d1) || (od1 == d1 && oi1 < i1);
    const float w1  = lt1 ? od1 : d1;   const int wi1 = lt1 ? oi1 : i1;
    const float l1  = lt1 ? d1  : od1;  const int li1 = lt1 ? i1  : oi1;
    const float w2  = lt1 ? od2 : d2;   const int wi2 = lt1 ? oi2 : i2;
    const bool  lt2 = (l1 < w2) || (l1 == w2 && li1 < wi2);
    d1 = w1; i1 = wi1;
    d2 = lt2 ? l1 : w2;  i2 = lt2 ? li1 : wi2;
}

// Strict-< top-2 update for point k; enc = (slab<<2)|e packs the candidate
// (true index = 256*slab + 4*lane + e, monotone in enc within a lane, so
// strict < reproduces stable-argsort first-occurrence semantics).
#define UPDK(k, a, enc) {                                         \
    const bool lt1 = (a) < b1[k];                                 \
    const bool lt2 = (a) < b2[k];                                 \
    j2[k] = lt1 ? j1[k] : (lt2 ? (enc) : j2[k]);                  \
    j1[k] = lt1 ? (enc) : j1[k];                                  \
    b2[k] = fminf(b2[k], fmaxf(b1[k], (a)));                      \
    b1[k] = fminf(b1[k], (a)); }

// Kernel A: one wave per 8 consecutive points. Lanes scan float4 candidate
// chunks from LDS, keep 8 independent lexicographic top-2 states (ILP=8),
// butterfly-merge across lanes -> stable argsort[...,1] per point.
__global__ __launch_bounds__(256) void DE_89404039234069_nn(
    const float* __restrict__ y, const float* __restrict__ x,
    float* __restrict__ out, double* __restrict__ psum, double* __restrict__ psq)
{
    __shared__ float xs[NN];

    const int tid  = threadIdx.x;
    const int blk  = blockIdx.x;        // 512 blocks, 64 per batch
    const int b    = blk >> 6;
    const int base = b * NN;

    // Stage batch x into LDS (8 KB), float4-coalesced.
    const float4* xg  = (const float4*)(x + base);
    float4*       xs4 = (float4*)xs;
    xs4[tid]       = xg[tid];
    xs4[tid + 256] = xg[tid + 256];
    __syncthreads();

    const int wave = tid >> 6, lane = tid & 63;
    const int i0   = (blk & 63) * 32 + wave * 8;   // first of 8 points (mult of 8)

    float xi[PW], b1[PW], b2[PW];
    int   j1[PW], j2[PW];
    #pragma unroll
    for (int k = 0; k < PW; ++k) {
        xi[k] = xs[i0 + k];
        b1[k] = 1e30f; b2[k] = 1e30f; j1[k] = 0; j2[k] = 0;
    }

    if (i0 < NC) {
        // Context points: candidates [0, NC) -> exactly 4 unmasked slabs.
        #pragma unroll
        for (int s = 0; s < 4; ++s) {
            const float4 v = xs4[(s << 6) + lane];
            #pragma unroll
            for (int k = 0; k < PW; ++k) {
                UPDK(k, fabsf(v.x - xi[k]), 4 * s + 0);
                UPDK(k, fabsf(v.y - xi[k]), 4 * s + 1);
                UPDK(k, fabsf(v.z - xi[k]), 4 * s + 2);
                UPDK(k, fabsf(v.w - xi[k]), 4 * s + 3);
            }
        }
    } else {
        // Target point i: candidates [0, i+1). Slabs fully below min limit
        // (i0+1) are unmasked; the 1-2 tail slabs mask per point.
        const int F      = (i0 + 1) >> 8;
        const int maxlim = i0 + 8;                  // last point's limit
        int s = 0;
        for (; s < F; ++s) {
            const float4 v = xs4[(s << 6) + lane];
            const int e0 = 4 * s;
            #pragma unroll
            for (int k = 0; k < PW; ++k) {
                UPDK(k, fabsf(v.x - xi[k]), e0 + 0);
                UPDK(k, fabsf(v.y - xi[k]), e0 + 1);
                UPDK(k, fabsf(v.z - xi[k]), e0 + 2);
                UPDK(k, fabsf(v.w - xi[k]), e0 + 3);
            }
        }
        for (; (s << 8) < maxlim; ++s) {
            const float4 v  = xs4[(s << 6) + lane];
            const int    p0 = (s << 8) + (lane << 2);
            const int    e0 = 4 * s;
            #pragma unroll
            for (int k = 0; k < PW; ++k) {
                const int lim = i0 + k + 1;         // candidate p valid iff p < lim
                const float a0 = (p0     < lim) ? fabsf(v.x - xi[k]) : 1e30f;
                const float a1 = (p0 + 1 < lim) ? fabsf(v.y - xi[k]) : 1e30f;
                const float a2 = (p0 + 2 < lim) ? fabsf(v.z - xi[k]) : 1e30f;
                const float a3 = (p0 + 3 < lim) ? fabsf(v.w - xi[k]) : 1e30f;
                UPDK(k, a0, e0 + 0);
                UPDK(k, a1, e0 + 1);
                UPDK(k, a2, e0 + 2);
                UPDK(k, a3, e0 + 3);
            }
        }
    }

    // Decode packed enc -> true candidate index, then butterfly-merge.
    float D1[PW], D2[PW];
    int   J1[PW], J2[PW];
    #pragma unroll
    for (int k = 0; k < PW; ++k) {
        D1[k] = b1[k]; D2[k] = b2[k];
        J1[k] = ((j1[k] >> 2) << 8) | (lane << 2) | (j1[k] & 3);
        J2[k] = ((j2[k] >> 2) << 8) | (lane << 2) | (j2[k] & 3);
    }
    for (int off = 1; off < 64; off <<= 1) {
        #pragma unroll
        for (int k = 0; k < PW; ++k) {
            const float od1 = __shfl_xor(D1[k], off, 64);
            const int   oi1 = __shfl_xor(J1[k], off, 64);
            const float od2 = __shfl_xor(D2[k], off, 64);
            const int   oi2 = __shfl_xor(J2[k], off, 64);
            lex_merge(D1[k], J1[k], D2[k], J2[k], od1, oi1, od2, oi2);
        }
    }

    if (lane == 0) {
        // Vectorized epilogue for the wave's 8 consecutive points.
        const float4 yi4a = ((const float4*)(y + base + i0))[0];
        const float4 yi4b = ((const float4*)(y + base + i0))[1];
        const float yiv[PW] = { yi4a.x, yi4a.y, yi4a.z, yi4a.w,
                                yi4b.x, yi4b.y, yi4b.z, yi4b.w };
        float yd[PW], xd[PW], dn[PW], lb[PW], xnv[PW], ynv[PW];
        double s = 0.0, q = 0.0;
        #pragma unroll
        for (int k = 0; k < PW; ++k) {
            const int   j    = J2[k];               // stable argsort[..., 1]
            const float xj   = xs[j];
            const float yj   = y[base + j];
            const float xrep = xi[k] - xj;
            const float yrep = yiv[k] - yj;
            const float d    = yrep / (2e-6f + fabsf(xrep));
            const float d1v  = (d != d) ? 10000.0f : d;
            const float d2v  = (fabsf(d) > 200.0f) ? 0.0f : d;
            yd[k]  = yrep; xd[k] = xrep; xnv[k] = xj; ynv[k] = yj;
            dn[k]  = d2v;
            lb[k]  = (d2v == d1v) ? 1.0f : 0.0f;
            s += (double)d2v; q += (double)d2v * (double)d2v;
        }
        const int gi = base + i0;
        float4* oyd = (float4*)(out + OFF_YDIFF + gi);
        float4* oxd = (float4*)(out + OFF_XDIFF + gi);
        float4* oxn = (float4*)(out + OFF_XN + gi);
        float4* oyn = (float4*)(out + OFF_YN + gi);
        float4* odo = (float4*)(out + OFF_DOUT + 2 * gi);
        oyd[0] = make_float4(yd[0], yd[1], yd[2], yd[3]);
        oyd[1] = make_float4(yd[4], yd[5], yd[6], yd[7]);
        oxd[0] = make_float4(xd[0], xd[1], xd[2], xd[3]);
        oxd[1] = make_float4(xd[4], xd[5], xd[6], xd[7]);
        oxn[0] = make_float4(xnv[0], xnv[1], xnv[2], xnv[3]);
        oxn[1] = make_float4(xnv[4], xnv[5], xnv[6], xnv[7]);
        oyn[0] = make_float4(ynv[0], ynv[1], ynv[2], ynv[3]);
        oyn[1] = make_float4(ynv[4], ynv[5], ynv[6], ynv[7]);
        odo[0] = make_float4(dn[0], lb[0], dn[1], lb[1]);
        odo[1] = make_float4(dn[2], lb[2], dn[3], lb[3]);
        odo[2] = make_float4(dn[4], lb[4], dn[5], lb[5]);
        odo[3] = make_float4(dn[6], lb[6], dn[7], lb[7]);
        const int gw = blk * 4 + wave;              // 0..NWAVE-1
        psum[gw] = s;
        psq[gw]  = q;
    }
}

// Kernel B: redundant per-block reduce of the 2048 partials, then batch-norm
// the stashed d2 values in place.
__global__ __launch_bounds__(256) void DE_89404039234069_bn(
    float* __restrict__ out, const double* __restrict__ psum,
    const double* __restrict__ psq,
    const float* __restrict__ bw, const float* __restrict__ bb)
{
    __shared__ double ws[4], wq[4];
    __shared__ float mean_s, scale_s;

    const int tid = threadIdx.x;
    double s = 0.0, q = 0.0;
    for (int k = tid; k < NWAVE; k += 256) { s += psum[k]; q += psq[k]; }
    #pragma unroll
    for (int off = 32; off > 0; off >>= 1) {
        s += __shfl_down(s, off, 64);
        q += __shfl_down(q, off, 64);
    }
    const int lane = tid & 63, wave = tid >> 6;
    if (lane == 0) { ws[wave] = s; wq[wave] = q; }
    __syncthreads();
    if (tid == 0) {
        const double S = ws[0] + ws[1] + ws[2] + ws[3];
        const double Q = wq[0] + wq[1] + wq[2] + wq[3];
        const double mean = S * (1.0 / (double)TOT);
        const double var  = Q * (1.0 / (double)TOT) - mean * mean;
        mean_s  = (float)mean;
        scale_s = (float)(1.0 / sqrt(var + 1e-5));
    }
    __syncthreads();

    const float w    = bw[0];
    const float bias = bb[0];
    const int   idx  = blockIdx.x * 256 + tid;     // 0..TOT-1
    const float v    = out[OFF_DOUT + 2 * idx];
    out[OFF_DOUT + 2 * idx] = (v - mean_s) * scale_s * w + bias;
}

extern "C" void kernel_launch(void* const* d_in, const int* in_sizes, int n_in,
                              void* d_out, int out_size, void* d_ws, size_t ws_size,
                              hipStream_t stream)
{
    const float* y  = (const float*)d_in[0];
    const float* x  = (const float*)d_in[1];
    const float* bw = (const float*)d_in[2];
    const float* bb = (const float*)d_in[3];
    // d_in[4]=n_C, d_in[5]=n_T fixed at 1024 by setup_inputs (hard-coded).
    float*  out  = (float*)d_out;
    double* psum = (double*)d_ws;
    double* psq  = psum + NWAVE;

    DE_89404039234069_nn<<<NBLK, 256, 0, stream>>>(y, x, out, psum, psq);
    DE_89404039234069_bn<<<64, 256, 0, stream>>>(out, psum, psq, bw, bb);
}

// Round 4
// 83.404 us; speedup vs baseline: 1.0208x; 1.0208x over previous
//
#include <hip/hip_runtime.h>

// Problem constants (from setup_inputs): B=8, N=2048, n_C=n_T=1024, D=1.
#define BB   8
#define NN   2048
#define NC   1024
#define TOT  (BB * NN)          // 16384 points total
#define PW   4                  // points per wave
#define NWAVE (TOT / PW)        // 4096 waves
#define NBLK  (NWAVE / 4)       // 1024 blocks of 4 waves (16 points/block)

// Output layout (flat float32, reference tuple order):
//   y_diff[TOT], x_diff[TOT], d_out[TOT*2], x_n[TOT], y_n[TOT]
#define OFF_YDIFF 0
#define OFF_XDIFF (TOT)
#define OFF_DOUT  (2 * TOT)
#define OFF_XN    (4 * TOT)
#define OFF_YN    (5 * TOT)

// Lexicographic (dist, idx) merge of two sorted top-2 lists -> top-2 of union.
__device__ __forceinline__ void lex_merge(float& d1, int& i1, float& d2, int& i2,
                                          float od1, int oi1, float od2, int oi2)
{
    const bool  lt1 = (od1 < d1) || (od1 == d1 && oi1 < i1);
    const float w1  = lt1 ? od1 : d1;   const int wi1 = lt1 ? oi1 : i1;
    const float l1  = lt1 ? d1  : od1;  const int li1 = lt1 ? i1  : oi1;
    const float w2  = lt1 ? od2 : d2;   const int wi2 = lt1 ? oi2 : i2;
    const bool  lt2 = (l1 < w2) || (l1 == w2 && li1 < wi2);
    d1 = w1; i1 = wi1;
    d2 = lt2 ? l1 : w2;  i2 = lt2 ? li1 : wi2;
}

// Strict-< top-2 update for point k; enc = (slab<<2)|e packs the candidate
// (true index = 256*slab + 4*lane + e, monotone in enc within a lane, so
// strict < reproduces stable-argsort first-occurrence semantics).
#define UPDK(k, a, enc) {                                         \
    const bool lt1 = (a) < b1[k];                                 \
    const bool lt2 = (a) < b2[k];                                 \
    j2[k] = lt1 ? j1[k] : (lt2 ? (enc) : j2[k]);                  \
    j1[k] = lt1 ? (enc) : j1[k];                                  \
    b2[k] = fminf(b2[k], fmaxf(b1[k], (a)));                      \
    b1[k] = fminf(b1[k], (a)); }

// Kernel A: one wave per 4 consecutive points. Lanes scan float4 candidate
// chunks from LDS, keep 4 independent lexicographic top-2 states (ILP=4),
// butterfly-merge across lanes -> stable argsort[...,1] per point.
__global__ __launch_bounds__(256) void DE_89404039234069_nn(
    const float* __restrict__ y, const float* __restrict__ x,
    float* __restrict__ out, double* __restrict__ psum, double* __restrict__ psq)
{
    __shared__ float xs[NN];
    __shared__ float ys[NN];

    const int tid  = threadIdx.x;
    const int blk  = blockIdx.x;        // 1024 blocks, 128 per batch
    const int b    = blk >> 7;
    const int base = b * NN;

    // Stage batch x and y into LDS (2 x 8 KB), float4-coalesced.
    const float4* xg  = (const float4*)(x + base);
    const float4* yg  = (const float4*)(y + base);
    float4*       xs4 = (float4*)xs;
    float4*       ys4 = (float4*)ys;
    xs4[tid]       = xg[tid];
    xs4[tid + 256] = xg[tid + 256];
    ys4[tid]       = yg[tid];
    ys4[tid + 256] = yg[tid + 256];
    __syncthreads();

    const int wave = tid >> 6, lane = tid & 63;
    const int i0   = (blk & 127) * 16 + wave * 4;  // first of 4 points (mult of 4)

    float xi[PW], b1[PW], b2[PW];
    int   j1[PW], j2[PW];
    #pragma unroll
    for (int k = 0; k < PW; ++k) {
        xi[k] = xs[i0 + k];
        b1[k] = 1e30f; b2[k] = 1e30f; j1[k] = 0; j2[k] = 0;
    }

    if (i0 < NC) {
        // Context points: candidates [0, NC) -> exactly 4 unmasked slabs.
        #pragma unroll
        for (int s = 0; s < 4; ++s) {
            const float4 v = xs4[(s << 6) + lane];
            #pragma unroll
            for (int k = 0; k < PW; ++k) {
                UPDK(k, fabsf(v.x - xi[k]), 4 * s + 0);
                UPDK(k, fabsf(v.y - xi[k]), 4 * s + 1);
                UPDK(k, fabsf(v.z - xi[k]), 4 * s + 2);
                UPDK(k, fabsf(v.w - xi[k]), 4 * s + 3);
            }
        }
    } else {
        // Target point i: candidates [0, i+1). Slabs fully below min limit
        // (i0+1) are unmasked; the 1-2 tail slabs mask per point.
        const int F      = (i0 + 1) >> 8;
        const int maxlim = i0 + PW;                 // last point's limit
        int s = 0;
        for (; s < F; ++s) {
            const float4 v = xs4[(s << 6) + lane];
            const int e0 = 4 * s;
            #pragma unroll
            for (int k = 0; k < PW; ++k) {
                UPDK(k, fabsf(v.x - xi[k]), e0 + 0);
                UPDK(k, fabsf(v.y - xi[k]), e0 + 1);
                UPDK(k, fabsf(v.z - xi[k]), e0 + 2);
                UPDK(k, fabsf(v.w - xi[k]), e0 + 3);
            }
        }
        for (; (s << 8) < maxlim; ++s) {
            const float4 v  = xs4[(s << 6) + lane];
            const int    p0 = (s << 8) + (lane << 2);
            const int    e0 = 4 * s;
            #pragma unroll
            for (int k = 0; k < PW; ++k) {
                const int lim = i0 + k + 1;         // candidate p valid iff p < lim
                const float a0 = (p0     < lim) ? fabsf(v.x - xi[k]) : 1e30f;
                const float a1 = (p0 + 1 < lim) ? fabsf(v.y - xi[k]) : 1e30f;
                const float a2 = (p0 + 2 < lim) ? fabsf(v.z - xi[k]) : 1e30f;
                const float a3 = (p0 + 3 < lim) ? fabsf(v.w - xi[k]) : 1e30f;
                UPDK(k, a0, e0 + 0);
                UPDK(k, a1, e0 + 1);
                UPDK(k, a2, e0 + 2);
                UPDK(k, a3, e0 + 3);
            }
        }
    }

    // Decode packed enc -> true candidate index, then butterfly-merge.
    float D1[PW], D2[PW];
    int   J1[PW], J2[PW];
    #pragma unroll
    for (int k = 0; k < PW; ++k) {
        D1[k] = b1[k]; D2[k] = b2[k];
        J1[k] = ((j1[k] >> 2) << 8) | (lane << 2) | (j1[k] & 3);
        J2[k] = ((j2[k] >> 2) << 8) | (lane << 2) | (j2[k] & 3);
    }
    for (int off = 1; off < 64; off <<= 1) {
        #pragma unroll
        for (int k = 0; k < PW; ++k) {
            const float od1 = __shfl_xor(D1[k], off, 64);
            const int   oi1 = __shfl_xor(J1[k], off, 64);
            const float od2 = __shfl_xor(D2[k], off, 64);
            const int   oi2 = __shfl_xor(J2[k], off, 64);
            lex_merge(D1[k], J1[k], D2[k], J2[k], od1, oi1, od2, oi2);
        }
    }

    if (lane == 0) {
        // Vectorized epilogue for the wave's 4 consecutive points (LDS reads).
        float yd[PW], xd[PW], dn[PW], lb[PW], xnv[PW], ynv[PW];
        double s = 0.0, q = 0.0;
        #pragma unroll
        for (int k = 0; k < PW; ++k) {
            const int   j    = J2[k];               // stable argsort[..., 1]
            const float xj   = xs[j];
            const float yj   = ys[j];
            const float xrep = xi[k] - xj;
            const float yrep = ys[i0 + k] - yj;
            const float d    = yrep / (2e-6f + fabsf(xrep));
            const float d1v  = (d != d) ? 10000.0f : d;
            const float d2v  = (fabsf(d) > 200.0f) ? 0.0f : d;
            yd[k]  = yrep; xd[k] = xrep; xnv[k] = xj; ynv[k] = yj;
            dn[k]  = d2v;
            lb[k]  = (d2v == d1v) ? 1.0f : 0.0f;
            s += (double)d2v; q += (double)d2v * (double)d2v;
        }
        const int gi = base + i0;
        *(float4*)(out + OFF_YDIFF + gi) = make_float4(yd[0], yd[1], yd[2], yd[3]);
        *(float4*)(out + OFF_XDIFF + gi) = make_float4(xd[0], xd[1], xd[2], xd[3]);
        *(float4*)(out + OFF_XN + gi)    = make_float4(xnv[0], xnv[1], xnv[2], xnv[3]);
        *(float4*)(out + OFF_YN + gi)    = make_float4(ynv[0], ynv[1], ynv[2], ynv[3]);
        float4* odo = (float4*)(out + OFF_DOUT + 2 * gi);
        odo[0] = make_float4(dn[0], lb[0], dn[1], lb[1]);
        odo[1] = make_float4(dn[2], lb[2], dn[3], lb[3]);
        const int gw = blk * 4 + wave;              // 0..NWAVE-1
        psum[gw] = s;
        psq[gw]  = q;
    }
}

// Kernel B: redundant per-block reduce of the 4096 partials, then batch-norm
// the stashed d2 values in place.
__global__ __launch_bounds__(256) void DE_89404039234069_bn(
    float* __restrict__ out, const double* __restrict__ psum,
    const double* __restrict__ psq,
    const float* __restrict__ bw, const float* __restrict__ bb)
{
    __shared__ double ws[4], wq[4];
    __shared__ float mean_s, scale_s;

    const int tid = threadIdx.x;
    double s = 0.0, q = 0.0;
    for (int k = tid; k < NWAVE; k += 256) { s += psum[k]; q += psq[k]; }
    #pragma unroll
    for (int off = 32; off > 0; off >>= 1) {
        s += __shfl_down(s, off, 64);
        q += __shfl_down(q, off, 64);
    }
    const int lane = tid & 63, wave = tid >> 6;
    if (lane == 0) { ws[wave] = s; wq[wave] = q; }
    __syncthreads();
    if (tid == 0) {
        const double S = ws[0] + ws[1] + ws[2] + ws[3];
        const double Q = wq[0] + wq[1] + wq[2] + wq[3];
        const double mean = S * (1.0 / (double)TOT);
        const double var  = Q * (1.0 / (double)TOT) - mean * mean;
        mean_s  = (float)mean;
        scale_s = (float)(1.0 / sqrt(var + 1e-5));
    }
    __syncthreads();

    const float w    = bw[0];
    const float bias = bb[0];
    const int   idx  = blockIdx.x * 256 + tid;     // 0..TOT-1
    const float v    = out[OFF_DOUT + 2 * idx];
    out[OFF_DOUT + 2 * idx] = (v - mean_s) * scale_s * w + bias;
}

extern "C" void kernel_launch(void* const* d_in, const int* in_sizes, int n_in,
                              void* d_out, int out_size, void* d_ws, size_t ws_size,
                              hipStream_t stream)
{
    const float* y  = (const float*)d_in[0];
    const float* x  = (const float*)d_in[1];
    const float* bw = (const float*)d_in[2];
    const float* bb = (const float*)d_in[3];
    // d_in[4]=n_C, d_in[5]=n_T fixed at 1024 by setup_inputs (hard-coded).
    float*  out  = (float*)d_out;
    double* psum = (double*)d_ws;
    double* psq  = psum + NWAVE;

    DE_89404039234069_nn<<<NBLK, 256, 0, stream>>>(y, x, out, psum, psq);
    DE_89404039234069_bn<<<64, 256, 0, stream>>>(out, psum, psq, bw, bb);
}